// Round 1
// baseline (4932.524 us; speedup 1.0000x reference)
//
#include <hip/hip_runtime.h>
#include <cstdint>
#include <cstddef>

// ---------------- problem constants ----------------
#define NN 8192      // nodes (= LSTM sequence length)
#define FIN 1280
#define HID 320
#define FOUR_H 1280
#define NE 131072
#define NG 1024

// scan decomposition
#define TEAMS 51
#define TPB_TEAM 5
#define CHUNK_L 161   // ceil(8192/51)
#define BURN 96       // burn-in steps; contraction ~0.5/step -> error << 1e-9

typedef unsigned short u16;
typedef __attribute__((ext_vector_type(8))) short bf16x8;   // per guide §3 (4 VGPRs)
typedef __attribute__((ext_vector_type(4))) float f32x4;

__device__ __forceinline__ float lrelu(float x){ return x > 0.f ? x : 0.01f*x; }
__device__ __forceinline__ u16 f2bf(float f){
  unsigned u = __float_as_uint(f);
  u = (u + 0x7FFFu + ((u >> 16) & 1u)) >> 16;   // RNE
  return (u16)u;
}

// ---------------- small prep kernels ----------------
__global__ void k_zero(int* deg, int* cnt){
  int i = blockIdx.x*256 + threadIdx.x;
  if (i < NN) deg[i] = 0;
  if (i < 256) cnt[i] = 0;
}

__global__ void k_bias(const float* bi0, const float* bh0, const float* bi1, const float* bh1,
                       float* bs0, float* bs1){
  int i = blockIdx.x*256 + threadIdx.x;
  if (i < 1280) bs0[i] = bi0[i] + bh0[i];
  else if (i < 2560) { int j = i - 1280; bs1[j] = bi1[j] + bh1[j]; }
}

// fp32 -> bf16 convert (optionally leaky-relu), with zero-padded output columns
__global__ void k_cvt(const float* __restrict__ in, u16* __restrict__ out,
                      int cin, int cout, int lrFlag){
  int c = blockIdx.x*256 + threadIdx.x;
  int r = blockIdx.y;
  if (c >= cout) return;
  float v = (c < cin) ? in[(size_t)r*cin + c] : 0.f;
  if (lrFlag) v = lrelu(v);
  out[(size_t)r*cout + c] = f2bf(v);
}

// W [K,N] fp32 -> WT [n][k] bf16, zero padded to [NR][KC]
__global__ void k_wT(const float* __restrict__ W, u16* __restrict__ WT,
                     int K, int Nn, int KC){
  int n = blockIdx.x;
  int k = blockIdx.y*256 + threadIdx.x;
  if (k >= KC) return;
  float v = (n < Nn && k < K) ? W[(size_t)k*Nn + n] : 0.f;
  WT[(size_t)n*KC + k] = f2bf(v);
}

// ---------------- bf16 MFMA GEMM: C[M,N] = A[M,K] * B[N,K]^T + bias ----------------
// A,B row-major, K-contiguous. Tile 64x64 per block (256 thr = 4 waves),
// wave w does rows [w*16,w*16+16) x all 64 cols. Verified m89/m91 layouts.
__global__ __launch_bounds__(256) void gemm_bt(
    const u16* __restrict__ A, int lda,
    const u16* __restrict__ B, int ldb,
    float* __restrict__ C, int ldc, int Nn, int kIters,
    const float* __restrict__ bias)
{
  __shared__ __align__(16) u16 As[64][40];   // 32 K-elems padded to 40 (bank-conflict-free)
  __shared__ __align__(16) u16 Bs[64][40];
  int t = threadIdx.x; int wv = t >> 6; int ln = t & 63;
  int m0 = blockIdx.x*64, n0 = blockIdx.y*64;
  f32x4 acc0 = {0,0,0,0}, acc1 = {0,0,0,0}, acc2 = {0,0,0,0}, acc3 = {0,0,0,0};
  int sr = t >> 2, sc = (t & 3) * 8;
  const u16* Ap = A + (size_t)(m0+sr)*lda + sc;
  const u16* Bp = B + (size_t)(n0+sr)*ldb + sc;
  int fr = ln & 15, quad = ln >> 4;
  for (int kt = 0; kt < kIters; ++kt){
    uint4 av = *(const uint4*)(Ap + kt*32);
    uint4 bv = *(const uint4*)(Bp + kt*32);
    *(uint4*)(&As[sr][sc]) = av;
    *(uint4*)(&Bs[sr][sc]) = bv;
    __syncthreads();
    bf16x8 af = *(const bf16x8*)(&As[wv*16 + fr][quad*8]);
    bf16x8 b0 = *(const bf16x8*)(&Bs[     fr][quad*8]);
    bf16x8 b1 = *(const bf16x8*)(&Bs[16 + fr][quad*8]);
    bf16x8 b2 = *(const bf16x8*)(&Bs[32 + fr][quad*8]);
    bf16x8 b3 = *(const bf16x8*)(&Bs[48 + fr][quad*8]);
    acc0 = __builtin_amdgcn_mfma_f32_16x16x32_bf16(af, b0, acc0, 0, 0, 0);
    acc1 = __builtin_amdgcn_mfma_f32_16x16x32_bf16(af, b1, acc1, 0, 0, 0);
    acc2 = __builtin_amdgcn_mfma_f32_16x16x32_bf16(af, b2, acc2, 0, 0, 0);
    acc3 = __builtin_amdgcn_mfma_f32_16x16x32_bf16(af, b3, acc3, 0, 0, 0);
    __syncthreads();
  }
  f32x4 av4[4] = {acc0, acc1, acc2, acc3};
  int row0 = m0 + wv*16 + quad*4;
  #pragma unroll
  for (int nt = 0; nt < 4; ++nt){
    int col = n0 + nt*16 + fr;
    if (col < Nn){
      float bb = bias ? bias[col] : 0.f;
      #pragma unroll
      for (int i = 0; i < 4; ++i)
        C[(size_t)(row0+i)*ldc + col] = av4[nt][i] + bb;
    }
  }
}

// ---------------- chunked-parallel LSTM scan ----------------
// 51 teams x 5 blocks. Block (team,m) owns hidden units [64m,64m+64) => 256 W_hh rows,
// register-resident fp32 (160 VGPR/thread, 512 thr). Per step: matvec -> gates ->
// (c,h) update on wave0 -> publish 64-float h slice via agent-scope stores -> ticket sync.
__global__ __launch_bounds__(512, 2) void lstm_scan(
    const float* __restrict__ gx, const float* __restrict__ Whh,
    float* __restrict__ hout, float* hbuf, int* cnt)
{
  int b = blockIdx.x;
  int team = b / TPB_TEAM, m = b % TPB_TEAM;
  int cstart = team * CHUNK_L;
  int cend   = min(NN, cstart + CHUNK_L);
  int s0     = max(0, cstart - BURN);
  int t = threadIdx.x;
  int r = t >> 1, kh = t & 1;          // r: 0..255 gate-row, kh: K half
  int lg = r >> 6, jl = r & 63;        // gate index, local unit
  int wrow = lg*HID + m*64 + jl;       // row in W_hh / col in gx
  float w[160];
  {
    const float4* wp = (const float4*)(Whh + (size_t)wrow*HID + kh*160);
    #pragma unroll
    for (int q = 0; q < 40; q++) ((float4*)w)[q] = wp[q];
  }
  __shared__ __align__(16) float h_lds[320];
  __shared__ float gates[256];
  for (int i = t; i < 320; i += 512) h_lds[i] = 0.f;
  float c = 0.f;                        // cell state lives in threads t<64
  float* hb = hbuf + (size_t)team * 2 * HID;
  int*   cn = cnt + team * 2;
  __syncthreads();
  int nsteps = cend - s0;
  for (int sl = 0; sl < nsteps; ++sl){
    int s = s0 + sl;
    int par = sl & 1;
    float gxv = 0.f;
    if (kh == 0) gxv = gx[(size_t)s*FOUR_H + wrow];
    const float4* hv = (const float4*)(h_lds + kh*160);
    float a0=0,a1=0,a2=0,a3=0,a4=0,a5=0,a6=0,a7=0;
    #pragma unroll
    for (int q = 0; q < 40; q += 2){
      float4 x0 = hv[q], x1 = hv[q+1];
      a0 += w[4*q+0]*x0.x; a1 += w[4*q+1]*x0.y;
      a2 += w[4*q+2]*x0.z; a3 += w[4*q+3]*x0.w;
      a4 += w[4*q+4]*x1.x; a5 += w[4*q+5]*x1.y;
      a6 += w[4*q+6]*x1.z; a7 += w[4*q+7]*x1.w;
    }
    float acc = ((a0+a1)+(a2+a3)) + ((a4+a5)+(a6+a7));
    acc += __shfl_xor(acc, 1, 64);     // combine K halves (lane pair)
    if (kh == 0) gates[r] = acc + gxv;
    __syncthreads();
    if (t < 64){
      float gi = gates[t], gf = gates[64+t], gg = gates[128+t], go = gates[192+t];
      float si = 1.f/(1.f + __expf(-gi));
      float sf = 1.f/(1.f + __expf(-gf));
      float tg = 1.f - 2.f/(1.f + __expf(2.f*gg));
      c = sf*c + si*tg;
      float th = 1.f - 2.f/(1.f + __expf(2.f*c));
      float h = (1.f/(1.f + __expf(-go))) * th;
      __hip_atomic_store(&hb[par*HID + m*64 + t], h, __ATOMIC_RELAXED, __HIP_MEMORY_SCOPE_AGENT);
      if (s >= cstart) hout[(size_t)s*HID + m*64 + t] = h;
    }
    __syncthreads();                   // drains vmcnt -> slice visible before ticket
    if (t == 0){
      __hip_atomic_fetch_add(&cn[par], 1, __ATOMIC_RELEASE, __HIP_MEMORY_SCOPE_AGENT);
      int target = TPB_TEAM * ((sl >> 1) + 1);
      while (__hip_atomic_load(&cn[par], __ATOMIC_ACQUIRE, __HIP_MEMORY_SCOPE_AGENT) < target) {}
    }
    __syncthreads();
    if (t < 320)
      h_lds[t] = __hip_atomic_load(&hb[par*HID + t], __ATOMIC_RELAXED, __HIP_MEMORY_SCOPE_AGENT);
    __syncthreads();
  }
}

// ---------------- GCN: CSR build (counting sort by dst) + gather ----------------
__global__ void k_hist(const int* __restrict__ ei, int* deg){
  int e = blockIdx.x*256 + threadIdx.x;
  if (e < NE) atomicAdd(&deg[ei[NE + e]], 1);
}

__global__ void k_offsets(const int* __restrict__ deg, int* off, int* cursor){
  __shared__ int sdata[1024];
  int t = threadIdx.x;
  int loc[8]; int s = 0;
  #pragma unroll
  for (int j = 0; j < 8; j++){ loc[j] = deg[t*8 + j]; s += loc[j]; }
  sdata[t] = s; __syncthreads();
  for (int d = 1; d < 1024; d <<= 1){
    int add = (t >= d) ? sdata[t-d] : 0;
    __syncthreads();
    sdata[t] += add;
    __syncthreads();
  }
  int run = sdata[t] - s;               // exclusive prefix of this chunk
  #pragma unroll
  for (int j = 0; j < 8; j++){ off[t*8+j] = run; cursor[t*8+j] = run; run += loc[j]; }
  if (t == 1023) off[NN] = run;
}

__global__ void k_scatter(const int* __restrict__ ei, const float* __restrict__ ew,
                          int* cursor, int* esrc, float* ews){
  int e = blockIdx.x*256 + threadIdx.x;
  if (e < NE){
    int d = ei[NE + e];
    int p = atomicAdd(&cursor[d], 1);
    esrc[p] = ei[e];
    ews[p] = ew[e];
  }
}

// one wave per dst node; acc[5] covers F<=320. outb!=null: bf16(+lr) padded store;
// else fp32 store (layer 4).
__global__ void k_gather(const float* __restrict__ XW, int F,
    const int* __restrict__ off, const int* __restrict__ esrc, const float* __restrict__ ews,
    const float* __restrict__ bias, u16* outb, float* outf, int ldout, int lrFlag)
{
  int node = blockIdx.x*4 + (threadIdx.x >> 6);
  int lane = threadIdx.x & 63;
  float acc[5] = {0,0,0,0,0};
  int e0 = off[node], e1 = off[node+1];
  for (int e = e0; e < e1; ++e){
    int sN = esrc[e]; float we = ews[e];
    const float* xr = XW + (size_t)sN*F;
    #pragma unroll
    for (int j = 0; j < 5; j++){
      int f = j*64 + lane;
      if (f < F) acc[j] += we * xr[f];
    }
  }
  #pragma unroll
  for (int j = 0; j < 5; j++){
    int f = j*64 + lane;
    if (f < F){
      float v = acc[j] + bias[f];
      if (lrFlag) v = lrelu(v);
      if (outb) outb[(size_t)node*ldout + f] = f2bf(v);
      else      outf[(size_t)node*F + f] = v;
    }
  }
  if (outb){
    for (int f = F + lane; f < ldout; f += 64) outb[(size_t)node*ldout + f] = 0;
  }
}

// ---------------- BN stats + fused BN/pool/FC ----------------
__global__ void k_bnstats(const float* __restrict__ conv4, float* mu, float* iv){
  int f = blockIdx.x, t = threadIdx.x;
  float s = 0, ss = 0;
  for (int i = t; i < NN; i += 256){ float v = conv4[(size_t)i*50 + f]; s += v; ss += v*v; }
  __shared__ float S[256], SS[256];
  S[t] = s; SS[t] = ss; __syncthreads();
  for (int d = 128; d > 0; d >>= 1){ if (t < d){ S[t] += S[t+d]; SS[t] += SS[t+d]; } __syncthreads(); }
  if (t == 0){
    float m = S[0] / (float)NN;
    float var = SS[0] / (float)NN - m*m;   // biased, training mode
    mu[f] = m; iv[f] = rsqrtf(var + 1e-5f);
  }
}

__global__ void k_final(const float* __restrict__ conv4, const float* __restrict__ mu,
    const float* __restrict__ iv, const float* __restrict__ gamma, const float* __restrict__ beta,
    const float* __restrict__ f1W, const float* __restrict__ f1b,
    const float* __restrict__ f2W, const float* __restrict__ f2b,
    const float* __restrict__ f3W, const float* __restrict__ f3b, float* __restrict__ out)
{
  int g = blockIdx.x, t = threadIdx.x;
  __shared__ float pl[50]; __shared__ float o1[30]; __shared__ float o2[20];
  if (t < 50){
    float mf = mu[t], ivf = iv[t], ga = gamma[t], be = beta[t];
    float s = 0;
    for (int i = 0; i < 8; i++){
      float v = conv4[(size_t)(g*8+i)*50 + t];
      v = ga*(v - mf)*ivf + be;
      s += lrelu(v);
    }
    pl[t] = s;
  }
  __syncthreads();
  if (t < 30){ float a = f1b[t]; for (int f = 0; f < 50; f++) a += pl[f]*f1W[f*30+t]; o1[t] = lrelu(a); }
  __syncthreads();
  if (t < 20){ float a = f2b[t]; for (int j = 0; j < 30; j++) a += o1[j]*f2W[j*20+t]; o2[t] = lrelu(a); }
  __syncthreads();
  if (t < 2){  float a = f3b[t]; for (int j = 0; j < 20; j++) a += o2[j]*f3W[j*2+t]; out[g*2+t] = lrelu(a); }
}

// ---------------- host ----------------
extern "C" void kernel_launch(void* const* d_in, const int* in_sizes, int n_in,
                              void* d_out, int out_size, void* d_ws, size_t ws_size,
                              hipStream_t stream) {
  const float* x    = (const float*)d_in[0];
  const int*   ei   = (const int*)  d_in[1];
  const float* ew   = (const float*)d_in[2];
  const float* Wih0 = (const float*)d_in[4];
  const float* Whh0 = (const float*)d_in[5];
  const float* bi0  = (const float*)d_in[6];
  const float* bh0  = (const float*)d_in[7];
  const float* Wih1 = (const float*)d_in[8];
  const float* Whh1 = (const float*)d_in[9];
  const float* bi1  = (const float*)d_in[10];
  const float* bh1  = (const float*)d_in[11];
  const float* Wg1  = (const float*)d_in[12];
  const float* bg1  = (const float*)d_in[13];
  const float* Wg2  = (const float*)d_in[14];
  const float* bg2  = (const float*)d_in[15];
  const float* Wg3  = (const float*)d_in[16];
  const float* bg3  = (const float*)d_in[17];
  const float* Wg4  = (const float*)d_in[18];
  const float* bg4  = (const float*)d_in[19];
  const float* gam  = (const float*)d_in[20];
  const float* bet  = (const float*)d_in[21];
  const float* f1W  = (const float*)d_in[22];
  const float* f1b  = (const float*)d_in[23];
  const float* f2W  = (const float*)d_in[24];
  const float* f2b  = (const float*)d_in[25];
  const float* f3W  = (const float*)d_in[26];
  const float* f3b  = (const float*)d_in[27];

  char* ws = (char*)d_ws;
  size_t o = 0;
  auto alloc = [&](size_t bytes)->char*{ char* p = ws + o; o += (bytes + 255) & ~(size_t)255; return p; };
  float* gx    = (float*)alloc((size_t)NN*FOUR_H*4);   // 40 MB, reused for gx0 then gx1
  float* hbuf0f= nullptr; // placed later
  float* hseq  = (float*)alloc((size_t)NN*HID*4);      // h0 then h1 (aliased)
  u16*   actA  = (u16*)  alloc((size_t)NN*FIN*2);      // xb -> gcn2 out
  u16*   actB  = (u16*)  alloc((size_t)NN*HID*2);      // h0b -> gcn1 out -> gcn3 out
  float* XW    = (float*)alloc((size_t)NN*HID*4);
  float* conv4 = (float*)alloc((size_t)NN*50*4);
  u16*   Wih0b = (u16*)  alloc((size_t)1280*1280*2);
  u16*   Wih1b = (u16*)  alloc((size_t)1280*320*2);
  u16*   W1T   = (u16*)  alloc((size_t)320*320*2);
  u16*   W2T   = (u16*)  alloc((size_t)192*320*2);
  u16*   W3T   = (u16*)  alloc((size_t)128*192*2);
  u16*   W4T   = (u16*)  alloc((size_t)64*96*2);
  float* bs0   = (float*)alloc(1280*4);
  float* bs1   = (float*)alloc(1280*4);
  float* mu    = (float*)alloc(256);
  float* iv    = (float*)alloc(256);
  int*   deg   = (int*)  alloc(NN*4);
  int*   off   = (int*)  alloc((NN+1)*4);
  int*   cursor= (int*)  alloc(NN*4);
  int*   esrc  = (int*)  alloc((size_t)NE*4);
  float* ews   = (float*)alloc((size_t)NE*4);
  float* hbuf0 = (float*)alloc((size_t)TEAMS*2*HID*4);
  float* hbuf1 = (float*)alloc((size_t)TEAMS*2*HID*4);
  int*   cnt   = (int*)  alloc(256*4);                 // [0..101] scan0, [128..229] scan1
  (void)hbuf0f; (void)ws_size; (void)in_sizes; (void)n_in; (void)out_size;

  // prep
  k_zero<<<32, 256, 0, stream>>>(deg, cnt);
  k_bias<<<10, 256, 0, stream>>>(bi0, bh0, bi1, bh1, bs0, bs1);
  k_cvt<<<dim3(5, NN),   256, 0, stream>>>(x,    actA,  1280, 1280, 0);
  k_cvt<<<dim3(5, 1280), 256, 0, stream>>>(Wih0, Wih0b, 1280, 1280, 0);
  k_cvt<<<dim3(2, 1280), 256, 0, stream>>>(Wih1, Wih1b, 320,  320,  0);
  k_wT<<<dim3(320, 2), 256, 0, stream>>>(Wg1, W1T, 320, 320, 320);
  k_wT<<<dim3(192, 2), 256, 0, stream>>>(Wg2, W2T, 320, 180, 320);
  k_wT<<<dim3(128, 1), 256, 0, stream>>>(Wg3, W3T, 180, 90, 192);
  k_wT<<<dim3(64, 1),  256, 0, stream>>>(Wg4, W4T, 90, 50, 96);
  // CSR build (graph fixed per-call; rebuilt every call)
  k_hist<<<512, 256, 0, stream>>>(ei, deg);
  k_offsets<<<1, 1024, 0, stream>>>(deg, off, cursor);
  k_scatter<<<512, 256, 0, stream>>>(ei, ew, cursor, esrc, ews);

  // LSTM layer 0
  gemm_bt<<<dim3(128, 20), 256, 0, stream>>>(actA, 1280, Wih0b, 1280, gx, 1280, 1280, 40, bs0);
  {
    const float* a0 = gx; const float* a1 = Whh0; float* a2 = hseq; float* a3 = hbuf0; int* a4 = cnt;
    void* kargs[5] = {&a0, &a1, &a2, &a3, &a4};
    if (hipLaunchCooperativeKernel((const void*)lstm_scan, dim3(TEAMS*TPB_TEAM), dim3(512),
                                   kargs, 0, stream) != hipSuccess)
      lstm_scan<<<dim3(TEAMS*TPB_TEAM), 512, 0, stream>>>(a0, a1, a2, a3, a4);
  }
  // LSTM layer 1
  k_cvt<<<dim3(2, NN), 256, 0, stream>>>(hseq, actB, 320, 320, 0);
  gemm_bt<<<dim3(128, 20), 256, 0, stream>>>(actB, 320, Wih1b, 320, gx, 1280, 1280, 10, bs1);
  {
    const float* a0 = gx; const float* a1 = Whh1; float* a2 = hseq; float* a3 = hbuf1; int* a4 = cnt + 128;
    void* kargs[5] = {&a0, &a1, &a2, &a3, &a4};
    if (hipLaunchCooperativeKernel((const void*)lstm_scan, dim3(TEAMS*TPB_TEAM), dim3(512),
                                   kargs, 0, stream) != hipSuccess)
      lstm_scan<<<dim3(TEAMS*TPB_TEAM), 512, 0, stream>>>(a0, a1, a2, a3, a4);
  }
  k_cvt<<<dim3(2, NN), 256, 0, stream>>>(hseq, actA, 320, 320, 1);  // leaky-relu -> gcn1 input

  // GCN stack
  gemm_bt<<<dim3(128, 5), 256, 0, stream>>>(actA, 320, W1T, 320, XW, 320, 320, 10, nullptr);
  k_gather<<<2048, 256, 0, stream>>>(XW, 320, off, esrc, ews, bg1, actB, nullptr, 320, 1);
  gemm_bt<<<dim3(128, 3), 256, 0, stream>>>(actB, 320, W2T, 320, XW, 180, 180, 10, nullptr);
  k_gather<<<2048, 256, 0, stream>>>(XW, 180, off, esrc, ews, bg2, actA, nullptr, 192, 1);
  gemm_bt<<<dim3(128, 2), 256, 0, stream>>>(actA, 192, W3T, 192, XW, 90, 90, 6, nullptr);
  k_gather<<<2048, 256, 0, stream>>>(XW, 90, off, esrc, ews, bg3, actB, nullptr, 96, 1);
  gemm_bt<<<dim3(128, 1), 256, 0, stream>>>(actB, 96, W4T, 96, XW, 50, 50, 3, nullptr);
  k_gather<<<2048, 256, 0, stream>>>(XW, 50, off, esrc, ews, bg4, nullptr, conv4, 50, 0);

  // BN (training-mode batch stats) + pool + FC head
  k_bnstats<<<50, 256, 0, stream>>>(conv4, mu, iv);
  k_final<<<NG, 64, 0, stream>>>(conv4, mu, iv, gam, bet, f1W, f1b, f2W, f2b, f3W, f3b,
                                 (float*)d_out);
}

// Round 2
// 1765.999 us; speedup vs baseline: 2.7931x; 2.7931x over previous
//
#include <hip/hip_runtime.h>
#include <cstdint>
#include <cstddef>

// ---------------- problem constants ----------------
#define NN 8192      // nodes (= LSTM sequence length)
#define FIN 1280
#define HID 320
#define FOUR_H 1280
#define NE 131072
#define NG 1024

// ---- chunked-parallel scan decomposition (MFMA-batched) ----
// 51 teams x 5 blocks; each team runs B_CH=16 chunks in lockstep.
// 816 chunks -> CHUNK_L=11 payload steps; BURN=48 burn-in (decay ~e^-1.1/step,
// 4-sigma worst case < 1e-10 at t=48).
#define TEAMS 51
#define TPB_TEAM 5
#define B_CH 16
#define CHUNK_L 11
#define BURN 48
#define NSTEPS (BURN + CHUNK_L)   // 59
#define HPAD 328                  // bf16 h row stride: 656B -> 2-way (free) LDS banks

typedef unsigned short u16;
typedef __attribute__((ext_vector_type(8))) short bf16x8;   // 4 VGPRs
typedef __attribute__((ext_vector_type(4))) float f32x4;

__device__ __forceinline__ float lrelu(float x){ return x > 0.f ? x : 0.01f*x; }
__device__ __forceinline__ u16 f2bf(float f){
  unsigned u = __float_as_uint(f);
  u = (u + 0x7FFFu + ((u >> 16) & 1u)) >> 16;   // RNE
  return (u16)u;
}

// ---------------- small prep kernels ----------------
__global__ void k_zero(int* deg, int* f0, int* f1){
  int i = blockIdx.x*256 + threadIdx.x;
  if (i < NN) deg[i] = 0;
  if (i < TEAMS*TPB_TEAM*32){ f0[i] = 0; f1[i] = 0; }
}

__global__ void k_bias(const float* bi0, const float* bh0, const float* bi1, const float* bh1,
                       float* bs0, float* bs1){
  int i = blockIdx.x*256 + threadIdx.x;
  if (i < 1280) bs0[i] = bi0[i] + bh0[i];
  else if (i < 2560) { int j = i - 1280; bs1[j] = bi1[j] + bh1[j]; }
}

// fp32 -> bf16 convert (optionally leaky-relu), with zero-padded output columns
__global__ void k_cvt(const float* __restrict__ in, u16* __restrict__ out,
                      int cin, int cout, int lrFlag){
  int c = blockIdx.x*256 + threadIdx.x;
  int r = blockIdx.y;
  if (c >= cout) return;
  float v = (c < cin) ? in[(size_t)r*cin + c] : 0.f;
  if (lrFlag) v = lrelu(v);
  out[(size_t)r*cout + c] = f2bf(v);
}

// W [K,N] fp32 -> WT [n][k] bf16, zero padded to [NR][KC]
__global__ void k_wT(const float* __restrict__ W, u16* __restrict__ WT,
                     int K, int Nn, int KC){
  int n = blockIdx.x;
  int k = blockIdx.y*256 + threadIdx.x;
  if (k >= KC) return;
  float v = (n < Nn && k < K) ? W[(size_t)k*Nn + n] : 0.f;
  WT[(size_t)n*KC + k] = f2bf(v);
}

// ---------------- bf16 MFMA GEMM: C[M,N] = A[M,K] * B[N,K]^T + bias ----------------
__global__ __launch_bounds__(256) void gemm_bt(
    const u16* __restrict__ A, int lda,
    const u16* __restrict__ B, int ldb,
    float* __restrict__ C, int ldc, int Nn, int kIters,
    const float* __restrict__ bias)
{
  __shared__ __align__(16) u16 As[64][40];
  __shared__ __align__(16) u16 Bs[64][40];
  int t = threadIdx.x; int wv = t >> 6; int ln = t & 63;
  int m0 = blockIdx.x*64, n0 = blockIdx.y*64;
  f32x4 acc0 = {0,0,0,0}, acc1 = {0,0,0,0}, acc2 = {0,0,0,0}, acc3 = {0,0,0,0};
  int sr = t >> 2, sc = (t & 3) * 8;
  const u16* Ap = A + (size_t)(m0+sr)*lda + sc;
  const u16* Bp = B + (size_t)(n0+sr)*ldb + sc;
  int fr = ln & 15, quad = ln >> 4;
  for (int kt = 0; kt < kIters; ++kt){
    uint4 av = *(const uint4*)(Ap + kt*32);
    uint4 bv = *(const uint4*)(Bp + kt*32);
    *(uint4*)(&As[sr][sc]) = av;
    *(uint4*)(&Bs[sr][sc]) = bv;
    __syncthreads();
    bf16x8 af = *(const bf16x8*)(&As[wv*16 + fr][quad*8]);
    bf16x8 b0 = *(const bf16x8*)(&Bs[     fr][quad*8]);
    bf16x8 b1 = *(const bf16x8*)(&Bs[16 + fr][quad*8]);
    bf16x8 b2 = *(const bf16x8*)(&Bs[32 + fr][quad*8]);
    bf16x8 b3 = *(const bf16x8*)(&Bs[48 + fr][quad*8]);
    acc0 = __builtin_amdgcn_mfma_f32_16x16x32_bf16(af, b0, acc0, 0, 0, 0);
    acc1 = __builtin_amdgcn_mfma_f32_16x16x32_bf16(af, b1, acc1, 0, 0, 0);
    acc2 = __builtin_amdgcn_mfma_f32_16x16x32_bf16(af, b2, acc2, 0, 0, 0);
    acc3 = __builtin_amdgcn_mfma_f32_16x16x32_bf16(af, b3, acc3, 0, 0, 0);
    __syncthreads();
  }
  f32x4 av4[4] = {acc0, acc1, acc2, acc3};
  int row0 = m0 + wv*16 + quad*4;
  #pragma unroll
  for (int nt = 0; nt < 4; ++nt){
    int col = n0 + nt*16 + fr;
    if (col < Nn){
      float bb = bias ? bias[col] : 0.f;
      #pragma unroll
      for (int i = 0; i < 4; ++i)
        C[(size_t)(row0+i)*ldc + col] = av4[nt][i] + bb;
    }
  }
}

// ---------------- MFMA-batched chunk-parallel LSTM scan ----------------
// Grid 255 = 51 teams x 5 blocks; block owns hidden units [blk*64, blk*64+64)
// for all 16 chunks of its team. Gate rows n_local = g*64+u (256 rows), weights
// bf16 B-fragments register-resident (wave w: rows [32w,32w+32) = 2 N-tiles).
// Per step: MFMA gates -> LDS -> c/h update -> publish own 16x64 h slice via
// LLC + per-block flag; poll 4 remote flags; pull remote slices into bf16 A-layout LDS.
__global__ __launch_bounds__(512, 2) void lstm_scan(
    const float* __restrict__ gx, const u16* __restrict__ Whh_bf,
    float* __restrict__ hout, float* pub, int* flags)
{
  int b = blockIdx.x;
  int team = b / TPB_TEAM, blk = b % TPB_TEAM;
  int t = threadIdx.x;
  int w = t >> 6, lane = t & 63;
  int fr = lane & 15, quad = lane >> 4;

  // register-resident weight fragments (no pointer casts through local arrays:
  // constant-indexed bf16x8 array -> SROA promotes; expect ~170-200 VGPRs)
  bf16x8 wf0[10], wf1[10];
  {
    int n0l = w*32 + fr;        // tile 0 row
    int n1l = w*32 + 16 + fr;   // tile 1 row
    int g0 = n0l >> 6, u0 = n0l & 63;
    int g1 = n1l >> 6, u1 = n1l & 63;
    const u16* wp0 = Whh_bf + (size_t)(g0*320 + blk*64 + u0)*320 + quad*8;
    const u16* wp1 = Whh_bf + (size_t)(g1*320 + blk*64 + u1)*320 + quad*8;
    #pragma unroll
    for (int kt = 0; kt < 10; ++kt){
      wf0[kt] = *(const bf16x8*)(wp0 + kt*32);
      wf1[kt] = *(const bf16x8*)(wp1 + kt*32);
    }
  }

  __shared__ __align__(16) u16 h_bf[2][B_CH][HPAD];   // bf16 h, A-frag layout
  __shared__ __align__(16) float gates[256][20];      // [n_local][chunk] (+pad)
  for (int i = t; i < 2*B_CH*HPAD; i += 512) ((u16*)h_bf)[i] = 0;

  // activation-side mapping: thread -> (chunk, units ul, ul+32)
  int chunk = t >> 5;
  int ul = t & 31;
  int cid = team*B_CH + chunk;
  int cstart = cid * CHUNK_L;
  int cend = min(NN, cstart + CHUNK_L);
  float c0 = 0.f, c1 = 0.f;
  float* pub_t = pub + (size_t)team * (2*TPB_TEAM*B_CH*64);
  int* flag_self = flags + b*32;
  __syncthreads();

  for (int sl = 0; sl < NSTEPS; ++sl){
    int par = sl & 1;
    int s = cstart - BURN + sl;
    bool sv = (s >= 0) && (s < NN);
    // prefetch gx early (consumed after the first barrier)
    float gxv[8];
    #pragma unroll
    for (int r = 0; r < 2; ++r)
      #pragma unroll
      for (int g = 0; g < 4; ++g)
        gxv[r*4+g] = sv ? gx[(size_t)s*FOUR_H + g*320 + blk*64 + ul + 32*r] : 0.f;

    // batched matvec: gates[16 chunks][256 rows] = h_bf[par] x W^T
    f32x4 acc0 = {0,0,0,0}, acc1 = {0,0,0,0};
    #pragma unroll
    for (int kt = 0; kt < 10; ++kt){
      bf16x8 a = *(const bf16x8*)(&h_bf[par][fr][kt*32 + quad*8]);
      acc0 = __builtin_amdgcn_mfma_f32_16x16x32_bf16(a, wf0[kt], acc0, 0, 0, 0);
      acc1 = __builtin_amdgcn_mfma_f32_16x16x32_bf16(a, wf1[kt], acc1, 0, 0, 0);
    }
    // C layout: chunk = quad*4+reg, row = tile*16+fr  -> store [row][chunk] as b128
    *(f32x4*)(&gates[w*32 +      fr][quad*4]) = acc0;
    *(f32x4*)(&gates[w*32 + 16 + fr][quad*4]) = acc1;
    __syncthreads();

    // c/h update for (chunk, ul) and (chunk, ul+32)
    float hv0, hv1;
    {
      int u = ul;
      float gi = gates[      u][chunk] + gxv[0];
      float gf = gates[ 64 + u][chunk] + gxv[1];
      float gg = gates[128 + u][chunk] + gxv[2];
      float go = gates[192 + u][chunk] + gxv[3];
      float si = 1.f/(1.f + __expf(-gi));
      float sf = 1.f/(1.f + __expf(-gf));
      float tg = 1.f - 2.f/(1.f + __expf(2.f*gg));
      c0 = sf*c0 + si*tg;
      float th = 1.f - 2.f/(1.f + __expf(2.f*c0));
      hv0 = (1.f/(1.f + __expf(-go))) * th;
    }
    {
      int u = ul + 32;
      float gi = gates[      u][chunk] + gxv[4];
      float gf = gates[ 64 + u][chunk] + gxv[5];
      float gg = gates[128 + u][chunk] + gxv[6];
      float go = gates[192 + u][chunk] + gxv[7];
      float si = 1.f/(1.f + __expf(-gi));
      float sf = 1.f/(1.f + __expf(-gf));
      float tg = 1.f - 2.f/(1.f + __expf(2.f*gg));
      c1 = sf*c1 + si*tg;
      float th = 1.f - 2.f/(1.f + __expf(2.f*c1));
      hv1 = (1.f/(1.f + __expf(-go))) * th;
    }
    // own h -> local LDS (next-step A buffer) + LLC publish + payload store
    h_bf[par^1][chunk][blk*64 + ul     ] = f2bf(hv0);
    h_bf[par^1][chunk][blk*64 + ul + 32] = f2bf(hv1);
    __hip_atomic_store(&pub_t[par*(TPB_TEAM*1024) + blk*1024 + chunk*64 + ul],
                       hv0, __ATOMIC_RELAXED, __HIP_MEMORY_SCOPE_AGENT);
    __hip_atomic_store(&pub_t[par*(TPB_TEAM*1024) + blk*1024 + chunk*64 + ul + 32],
                       hv1, __ATOMIC_RELAXED, __HIP_MEMORY_SCOPE_AGENT);
    if (s >= cstart && s < cend){
      hout[(size_t)s*HID + blk*64 + ul     ] = hv0;
      hout[(size_t)s*HID + blk*64 + ul + 32] = hv1;
    }
    __syncthreads();                     // drains all stores (vmcnt(0) before barrier)
    if (t == 0)
      __hip_atomic_store(flag_self, sl+1, __ATOMIC_RELEASE, __HIP_MEMORY_SCOPE_AGENT);
    if (t < 4){
      int rb = t + (t >= blk);
      int* rf = flags + (team*TPB_TEAM + rb)*32;
      while (__hip_atomic_load(rf, __ATOMIC_ACQUIRE, __HIP_MEMORY_SCOPE_AGENT) <= sl)
        __builtin_amdgcn_s_sleep(1);
    }
    __syncthreads();
    // pull 4 remote 16x64 slices into h_bf[par^1]
    #pragma unroll
    for (int j = 0; j < 8; ++j){
      int i = t + 512*j;                 // 0..4095
      int rbi = i >> 10;
      int rb = rbi + (rbi >= blk);
      int rem = i & 1023;
      int ch = rem >> 6, uu = rem & 63;
      float hvr = __hip_atomic_load(&pub_t[par*(TPB_TEAM*1024) + rb*1024 + rem],
                                    __ATOMIC_RELAXED, __HIP_MEMORY_SCOPE_AGENT);
      h_bf[par^1][ch][rb*64 + uu] = f2bf(hvr);
    }
    __syncthreads();
  }
}

// ---------------- GCN: CSR build (counting sort by dst) + gather ----------------
__global__ void k_hist(const int* __restrict__ ei, int* deg){
  int e = blockIdx.x*256 + threadIdx.x;
  if (e < NE) atomicAdd(&deg[ei[NE + e]], 1);
}

__global__ void k_offsets(const int* __restrict__ deg, int* off, int* cursor){
  __shared__ int sdata[1024];
  int t = threadIdx.x;
  int loc[8]; int s = 0;
  #pragma unroll
  for (int j = 0; j < 8; j++){ loc[j] = deg[t*8 + j]; s += loc[j]; }
  sdata[t] = s; __syncthreads();
  for (int d = 1; d < 1024; d <<= 1){
    int add = (t >= d) ? sdata[t-d] : 0;
    __syncthreads();
    sdata[t] += add;
    __syncthreads();
  }
  int run = sdata[t] - s;
  #pragma unroll
  for (int j = 0; j < 8; j++){ off[t*8+j] = run; cursor[t*8+j] = run; run += loc[j]; }
  if (t == 1023) off[NN] = run;
}

__global__ void k_scatter(const int* __restrict__ ei, const float* __restrict__ ew,
                          int* cursor, int* esrc, float* ews){
  int e = blockIdx.x*256 + threadIdx.x;
  if (e < NE){
    int d = ei[NE + e];
    int p = atomicAdd(&cursor[d], 1);
    esrc[p] = ei[e];
    ews[p] = ew[e];
  }
}

__global__ void k_gather(const float* __restrict__ XW, int F,
    const int* __restrict__ off, const int* __restrict__ esrc, const float* __restrict__ ews,
    const float* __restrict__ bias, u16* outb, float* outf, int ldout, int lrFlag)
{
  int node = blockIdx.x*4 + (threadIdx.x >> 6);
  int lane = threadIdx.x & 63;
  float acc[5] = {0,0,0,0,0};
  int e0 = off[node], e1 = off[node+1];
  for (int e = e0; e < e1; ++e){
    int sN = esrc[e]; float we = ews[e];
    const float* xr = XW + (size_t)sN*F;
    #pragma unroll
    for (int j = 0; j < 5; j++){
      int f = j*64 + lane;
      if (f < F) acc[j] += we * xr[f];
    }
  }
  #pragma unroll
  for (int j = 0; j < 5; j++){
    int f = j*64 + lane;
    if (f < F){
      float v = acc[j] + bias[f];
      if (lrFlag) v = lrelu(v);
      if (outb) outb[(size_t)node*ldout + f] = f2bf(v);
      else      outf[(size_t)node*F + f] = v;
    }
  }
  if (outb){
    for (int f = F + lane; f < ldout; f += 64) outb[(size_t)node*ldout + f] = 0;
  }
}

// ---------------- BN stats + fused BN/pool/FC ----------------
__global__ void k_bnstats(const float* __restrict__ conv4, float* mu, float* iv){
  int f = blockIdx.x, t = threadIdx.x;
  float s = 0, ss = 0;
  for (int i = t; i < NN; i += 256){ float v = conv4[(size_t)i*50 + f]; s += v; ss += v*v; }
  __shared__ float S[256], SS[256];
  S[t] = s; SS[t] = ss; __syncthreads();
  for (int d = 128; d > 0; d >>= 1){ if (t < d){ S[t] += S[t+d]; SS[t] += SS[t+d]; } __syncthreads(); }
  if (t == 0){
    float m = S[0] / (float)NN;
    float var = SS[0] / (float)NN - m*m;
    mu[f] = m; iv[f] = rsqrtf(var + 1e-5f);
  }
}

__global__ void k_final(const float* __restrict__ conv4, const float* __restrict__ mu,
    const float* __restrict__ iv, const float* __restrict__ gamma, const float* __restrict__ beta,
    const float* __restrict__ f1W, const float* __restrict__ f1b,
    const float* __restrict__ f2W, const float* __restrict__ f2b,
    const float* __restrict__ f3W, const float* __restrict__ f3b, float* __restrict__ out)
{
  int g = blockIdx.x, t = threadIdx.x;
  __shared__ float pl[50]; __shared__ float o1[30]; __shared__ float o2[20];
  if (t < 50){
    float mf = mu[t], ivf = iv[t], ga = gamma[t], be = beta[t];
    float s = 0;
    for (int i = 0; i < 8; i++){
      float v = conv4[(size_t)(g*8+i)*50 + t];
      v = ga*(v - mf)*ivf + be;
      s += lrelu(v);
    }
    pl[t] = s;
  }
  __syncthreads();
  if (t < 30){ float a = f1b[t]; for (int f = 0; f < 50; f++) a += pl[f]*f1W[f*30+t]; o1[t] = lrelu(a); }
  __syncthreads();
  if (t < 20){ float a = f2b[t]; for (int j = 0; j < 30; j++) a += o1[j]*f2W[j*20+t]; o2[t] = lrelu(a); }
  __syncthreads();
  if (t < 2){  float a = f3b[t]; for (int j = 0; j < 20; j++) a += o2[j]*f3W[j*2+t]; out[g*2+t] = lrelu(a); }
}

// ---------------- host ----------------
extern "C" void kernel_launch(void* const* d_in, const int* in_sizes, int n_in,
                              void* d_out, int out_size, void* d_ws, size_t ws_size,
                              hipStream_t stream) {
  const float* x    = (const float*)d_in[0];
  const int*   ei   = (const int*)  d_in[1];
  const float* ew   = (const float*)d_in[2];
  const float* Wih0 = (const float*)d_in[4];
  const float* Whh0 = (const float*)d_in[5];
  const float* bi0  = (const float*)d_in[6];
  const float* bh0  = (const float*)d_in[7];
  const float* Wih1 = (const float*)d_in[8];
  const float* Whh1 = (const float*)d_in[9];
  const float* bi1  = (const float*)d_in[10];
  const float* bh1  = (const float*)d_in[11];
  const float* Wg1  = (const float*)d_in[12];
  const float* bg1  = (const float*)d_in[13];
  const float* Wg2  = (const float*)d_in[14];
  const float* bg2  = (const float*)d_in[15];
  const float* Wg3  = (const float*)d_in[16];
  const float* bg3  = (const float*)d_in[17];
  const float* Wg4  = (const float*)d_in[18];
  const float* bg4  = (const float*)d_in[19];
  const float* gam  = (const float*)d_in[20];
  const float* bet  = (const float*)d_in[21];
  const float* f1W  = (const float*)d_in[22];
  const float* f1b  = (const float*)d_in[23];
  const float* f2W  = (const float*)d_in[24];
  const float* f2b  = (const float*)d_in[25];
  const float* f3W  = (const float*)d_in[26];
  const float* f3b  = (const float*)d_in[27];

  char* ws = (char*)d_ws;
  size_t o = 0;
  auto alloc = [&](size_t bytes)->char*{ char* p = ws + o; o += (bytes + 255) & ~(size_t)255; return p; };
  float* gx    = (float*)alloc((size_t)NN*FOUR_H*4);
  float* hseq  = (float*)alloc((size_t)NN*HID*4);
  u16*   actA  = (u16*)  alloc((size_t)NN*FIN*2);
  u16*   actB  = (u16*)  alloc((size_t)NN*HID*2);
  float* XW    = (float*)alloc((size_t)NN*HID*4);
  float* conv4 = (float*)alloc((size_t)NN*50*4);
  u16*   Wih0b = (u16*)  alloc((size_t)1280*1280*2);
  u16*   Wih1b = (u16*)  alloc((size_t)1280*320*2);
  u16*   Whh0b = (u16*)  alloc((size_t)1280*320*2);
  u16*   Whh1b = (u16*)  alloc((size_t)1280*320*2);
  u16*   W1T   = (u16*)  alloc((size_t)320*320*2);
  u16*   W2T   = (u16*)  alloc((size_t)192*320*2);
  u16*   W3T   = (u16*)  alloc((size_t)128*192*2);
  u16*   W4T   = (u16*)  alloc((size_t)64*96*2);
  float* bs0   = (float*)alloc(1280*4);
  float* bs1   = (float*)alloc(1280*4);
  float* mu    = (float*)alloc(256);
  float* iv    = (float*)alloc(256);
  int*   deg   = (int*)  alloc(NN*4);
  int*   off   = (int*)  alloc((NN+1)*4);
  int*   cursor= (int*)  alloc(NN*4);
  int*   esrc  = (int*)  alloc((size_t)NE*4);
  float* ews   = (float*)alloc((size_t)NE*4);
  float* pub   = (float*)alloc((size_t)TEAMS*2*TPB_TEAM*B_CH*64*4);
  int*   flags0= (int*)  alloc((size_t)TEAMS*TPB_TEAM*32*4);
  int*   flags1= (int*)  alloc((size_t)TEAMS*TPB_TEAM*32*4);
  (void)ws_size; (void)in_sizes; (void)n_in; (void)out_size;

  // prep
  k_zero<<<32, 256, 0, stream>>>(deg, flags0, flags1);
  k_bias<<<10, 256, 0, stream>>>(bi0, bh0, bi1, bh1, bs0, bs1);
  k_cvt<<<dim3(5, NN),   256, 0, stream>>>(x,    actA,  1280, 1280, 0);
  k_cvt<<<dim3(5, 1280), 256, 0, stream>>>(Wih0, Wih0b, 1280, 1280, 0);
  k_cvt<<<dim3(2, 1280), 256, 0, stream>>>(Wih1, Wih1b, 320,  320,  0);
  k_cvt<<<dim3(2, 1280), 256, 0, stream>>>(Whh0, Whh0b, 320,  320,  0);
  k_cvt<<<dim3(2, 1280), 256, 0, stream>>>(Whh1, Whh1b, 320,  320,  0);
  k_wT<<<dim3(320, 2), 256, 0, stream>>>(Wg1, W1T, 320, 320, 320);
  k_wT<<<dim3(192, 2), 256, 0, stream>>>(Wg2, W2T, 320, 180, 320);
  k_wT<<<dim3(128, 1), 256, 0, stream>>>(Wg3, W3T, 180, 90, 192);
  k_wT<<<dim3(64, 1),  256, 0, stream>>>(Wg4, W4T, 90, 50, 96);
  // CSR build
  k_hist<<<512, 256, 0, stream>>>(ei, deg);
  k_offsets<<<1, 1024, 0, stream>>>(deg, off, cursor);
  k_scatter<<<512, 256, 0, stream>>>(ei, ew, cursor, esrc, ews);

  // LSTM layer 0
  gemm_bt<<<dim3(128, 20), 256, 0, stream>>>(actA, 1280, Wih0b, 1280, gx, 1280, 1280, 40, bs0);
  {
    const float* a0 = gx; const u16* a1 = Whh0b; float* a2 = hseq; float* a3 = pub; int* a4 = flags0;
    void* kargs[5] = {&a0, &a1, &a2, &a3, &a4};
    if (hipLaunchCooperativeKernel((const void*)lstm_scan, dim3(TEAMS*TPB_TEAM), dim3(512),
                                   kargs, 0, stream) != hipSuccess)
      lstm_scan<<<dim3(TEAMS*TPB_TEAM), 512, 0, stream>>>(a0, a1, a2, a3, a4);
  }
  // LSTM layer 1
  k_cvt<<<dim3(2, NN), 256, 0, stream>>>(hseq, actB, 320, 320, 0);
  gemm_bt<<<dim3(128, 20), 256, 0, stream>>>(actB, 320, Wih1b, 320, gx, 1280, 1280, 10, bs1);
  {
    const float* a0 = gx; const u16* a1 = Whh1b; float* a2 = hseq; float* a3 = pub; int* a4 = flags1;
    void* kargs[5] = {&a0, &a1, &a2, &a3, &a4};
    if (hipLaunchCooperativeKernel((const void*)lstm_scan, dim3(TEAMS*TPB_TEAM), dim3(512),
                                   kargs, 0, stream) != hipSuccess)
      lstm_scan<<<dim3(TEAMS*TPB_TEAM), 512, 0, stream>>>(a0, a1, a2, a3, a4);
  }
  k_cvt<<<dim3(2, NN), 256, 0, stream>>>(hseq, actA, 320, 320, 1);

  // GCN stack
  gemm_bt<<<dim3(128, 5), 256, 0, stream>>>(actA, 320, W1T, 320, XW, 320, 320, 10, nullptr);
  k_gather<<<2048, 256, 0, stream>>>(XW, 320, off, esrc, ews, bg1, actB, nullptr, 320, 1);
  gemm_bt<<<dim3(128, 3), 256, 0, stream>>>(actB, 320, W2T, 320, XW, 180, 180, 10, nullptr);
  k_gather<<<2048, 256, 0, stream>>>(XW, 180, off, esrc, ews, bg2, actA, nullptr, 192, 1);
  gemm_bt<<<dim3(128, 2), 256, 0, stream>>>(actA, 192, W3T, 192, XW, 90, 90, 6, nullptr);
  k_gather<<<2048, 256, 0, stream>>>(XW, 90, off, esrc, ews, bg3, actB, nullptr, 96, 1);
  gemm_bt<<<dim3(128, 1), 256, 0, stream>>>(actB, 96, W4T, 96, XW, 50, 50, 3, nullptr);
  k_gather<<<2048, 256, 0, stream>>>(XW, 50, off, esrc, ews, bg4, nullptr, conv4, 50, 0);

  // BN + pool + FC head
  k_bnstats<<<50, 256, 0, stream>>>(conv4, mu, iv);
  k_final<<<NG, 64, 0, stream>>>(conv4, mu, iv, gam, bet, f1W, f1b, f2W, f2b, f3W, f3b,
                                 (float*)d_out);
}

// Round 3
// 993.924 us; speedup vs baseline: 4.9627x; 1.7768x over previous
//
#include <hip/hip_runtime.h>
#include <cstdint>
#include <cstddef>

// ---------------- problem constants ----------------
#define NN 8192      // nodes (= LSTM sequence length)
#define FIN 1280
#define HID 320
#define FOUR_H 1280
#define NE 131072
#define NG 1024

// ---- chunked-parallel scan decomposition (MFMA-batched) ----
#define TEAMS 51
#define TPB_TEAM 5
#define B_CH 16
#define CHUNK_L 11
#define BURN 48
#define NSTEPS (BURN + CHUNK_L)   // 59
#define HPAD 328                  // bf16 h row stride
#define GPAD 260                  // gates_t row stride (floats)

typedef unsigned short u16;
typedef __attribute__((ext_vector_type(8))) short bf16x8;   // 4 VGPRs
typedef __attribute__((ext_vector_type(4))) float f32x4;

__device__ __forceinline__ float lrelu(float x){ return x > 0.f ? x : 0.01f*x; }
__device__ __forceinline__ u16 f2bf(float f){
  unsigned u = __float_as_uint(f);
  u = (u + 0x7FFFu + ((u >> 16) & 1u)) >> 16;   // RNE
  return (u16)u;
}

// ---------------- small prep kernels ----------------
__global__ void k_zero(int* deg, int* f0, int* f1){
  int i = blockIdx.x*256 + threadIdx.x;
  if (i < NN) deg[i] = 0;
  if (i < TEAMS*TPB_TEAM*32){ f0[i] = 0; f1[i] = 0; }
}

__global__ void k_bias(const float* bi0, const float* bh0, const float* bi1, const float* bh1,
                       float* bs0, float* bs1){
  int i = blockIdx.x*256 + threadIdx.x;
  if (i < 1280) bs0[i] = bi0[i] + bh0[i];
  else if (i < 2560) { int j = i - 1280; bs1[j] = bi1[j] + bh1[j]; }
}

// fp32 -> bf16 convert (optionally leaky-relu), with zero-padded output columns
__global__ void k_cvt(const float* __restrict__ in, u16* __restrict__ out,
                      int cin, int cout, int lrFlag){
  int c = blockIdx.x*256 + threadIdx.x;
  int r = blockIdx.y;
  if (c >= cout) return;
  float v = (c < cin) ? in[(size_t)r*cin + c] : 0.f;
  if (lrFlag) v = lrelu(v);
  out[(size_t)r*cout + c] = f2bf(v);
}

// W [K,N] fp32 -> WT [n][k] bf16, zero padded to [NR][KC]
__global__ void k_wT(const float* __restrict__ W, u16* __restrict__ WT,
                     int K, int Nn, int KC){
  int n = blockIdx.x;
  int k = blockIdx.y*256 + threadIdx.x;
  if (k >= KC) return;
  float v = (n < Nn && k < K) ? W[(size_t)k*Nn + n] : 0.f;
  WT[(size_t)n*KC + k] = f2bf(v);
}

// ---------------- bf16 MFMA GEMM: C[M,N] = A[M,K] * B[N,K]^T + bias ----------------
__global__ __launch_bounds__(256) void gemm_bt(
    const u16* __restrict__ A, int lda,
    const u16* __restrict__ B, int ldb,
    float* __restrict__ C, int ldc, int Nn, int kIters,
    const float* __restrict__ bias)
{
  __shared__ __align__(16) u16 As[64][40];
  __shared__ __align__(16) u16 Bs[64][40];
  int t = threadIdx.x; int wv = t >> 6; int ln = t & 63;
  int m0 = blockIdx.x*64, n0 = blockIdx.y*64;
  f32x4 acc0 = {0,0,0,0}, acc1 = {0,0,0,0}, acc2 = {0,0,0,0}, acc3 = {0,0,0,0};
  int sr = t >> 2, sc = (t & 3) * 8;
  const u16* Ap = A + (size_t)(m0+sr)*lda + sc;
  const u16* Bp = B + (size_t)(n0+sr)*ldb + sc;
  int fr = ln & 15, quad = ln >> 4;
  for (int kt = 0; kt < kIters; ++kt){
    uint4 av = *(const uint4*)(Ap + kt*32);
    uint4 bv = *(const uint4*)(Bp + kt*32);
    *(uint4*)(&As[sr][sc]) = av;
    *(uint4*)(&Bs[sr][sc]) = bv;
    __syncthreads();
    bf16x8 af = *(const bf16x8*)(&As[wv*16 + fr][quad*8]);
    bf16x8 b0 = *(const bf16x8*)(&Bs[     fr][quad*8]);
    bf16x8 b1 = *(const bf16x8*)(&Bs[16 + fr][quad*8]);
    bf16x8 b2 = *(const bf16x8*)(&Bs[32 + fr][quad*8]);
    bf16x8 b3 = *(const bf16x8*)(&Bs[48 + fr][quad*8]);
    acc0 = __builtin_amdgcn_mfma_f32_16x16x32_bf16(af, b0, acc0, 0, 0, 0);
    acc1 = __builtin_amdgcn_mfma_f32_16x16x32_bf16(af, b1, acc1, 0, 0, 0);
    acc2 = __builtin_amdgcn_mfma_f32_16x16x32_bf16(af, b2, acc2, 0, 0, 0);
    acc3 = __builtin_amdgcn_mfma_f32_16x16x32_bf16(af, b3, acc3, 0, 0, 0);
    __syncthreads();
  }
  f32x4 av4[4] = {acc0, acc1, acc2, acc3};
  int row0 = m0 + wv*16 + quad*4;
  #pragma unroll
  for (int nt = 0; nt < 4; ++nt){
    int col = n0 + nt*16 + fr;
    if (col < Nn){
      float bb = bias ? bias[col] : 0.f;
      #pragma unroll
      for (int i = 0; i < 4; ++i)
        C[(size_t)(row0+i)*ldc + col] = av4[nt][i] + bb;
    }
  }
}

// ---------------- MFMA-batched chunk-parallel LSTM scan ----------------
// Sync design note (R3): RELAXED agent-scope atomics ONLY in the hot loop.
// __syncthreads() already forces s_waitcnt vmcnt(0) per wave, so all sc1
// publish-stores are LLC-visible before the flag store is issued. ACQ/REL
// here emitted per-poll cache invalidates that destroyed device-wide L2
// locality (R2: FETCH 236MB, 10.3us/step).
__global__ __launch_bounds__(512, 2) void lstm_scan(
    const float* __restrict__ gx, const u16* __restrict__ Whh_bf,
    float* __restrict__ hout, unsigned* pub, int* flags)
{
  int b = blockIdx.x;
  int team = b / TPB_TEAM, blk = b % TPB_TEAM;
  int t = threadIdx.x;
  int w = t >> 6, lane = t & 63;
  int fr = lane & 15, quad = lane >> 4;

  // register-resident bf16 B-fragments of W_hh (2 N-tiles x 10 K-frags)
  bf16x8 wf0[10], wf1[10];
  {
    int n0l = w*32 + fr;
    int n1l = w*32 + 16 + fr;
    int g0 = n0l >> 6, u0 = n0l & 63;
    int g1 = n1l >> 6, u1 = n1l & 63;
    const u16* wp0 = Whh_bf + (size_t)(g0*320 + blk*64 + u0)*320 + quad*8;
    const u16* wp1 = Whh_bf + (size_t)(g1*320 + blk*64 + u1)*320 + quad*8;
    #pragma unroll
    for (int kt = 0; kt < 10; ++kt){
      wf0[kt] = *(const bf16x8*)(wp0 + kt*32);
      wf1[kt] = *(const bf16x8*)(wp1 + kt*32);
    }
  }

  __shared__ __align__(16) u16 h_bf[2][B_CH][HPAD];     // bf16 h, A-frag layout
  __shared__ __align__(16) float gates_t[B_CH][GPAD];   // [chunk][n_local] transposed
  for (int i = t; i < 2*B_CH*HPAD; i += 512) ((u16*)h_bf)[i] = 0;

  int chunk = t >> 5;
  int ul = t & 31;
  int cid = team*B_CH + chunk;
  int cstart = cid * CHUNK_L;
  int cend = min(NN, cstart + CHUNK_L);
  float c0 = 0.f, c1 = 0.f;
  unsigned* pub_t = pub + (size_t)team * (2*TPB_TEAM*512);
  int* flag_self = flags + b*32;
  __syncthreads();

  for (int sl = 0; sl < NSTEPS; ++sl){
    int par = sl & 1;
    int s = cstart - BURN + sl;
    bool sv = (s >= 0) && (s < NN);
    // prefetch gx (coalesced 128B per 32-lane group; consumed after barrier)
    float gxv[8];
    #pragma unroll
    for (int r = 0; r < 2; ++r)
      #pragma unroll
      for (int g = 0; g < 4; ++g)
        gxv[r*4+g] = sv ? gx[(size_t)s*FOUR_H + g*320 + blk*64 + ul + 32*r] : 0.f;

    // batched matvec: gates[16 chunks][256 rows] = h x W^T
    f32x4 acc0 = {0,0,0,0}, acc1 = {0,0,0,0};
    #pragma unroll
    for (int kt = 0; kt < 10; ++kt){
      bf16x8 a = *(const bf16x8*)(&h_bf[par][fr][kt*32 + quad*8]);
      acc0 = __builtin_amdgcn_mfma_f32_16x16x32_bf16(a, wf0[kt], acc0, 0, 0, 0);
      acc1 = __builtin_amdgcn_mfma_f32_16x16x32_bf16(a, wf1[kt], acc1, 0, 0, 0);
    }
    // C layout (chunk = quad*4+reg, row = tile*16+fr) -> transposed scatter
    // (scalar stores ~2-way: free; makes activation reads conflict-free)
    #pragma unroll
    for (int i = 0; i < 4; ++i){
      gates_t[quad*4+i][w*32 +      fr] = acc0[i];
      gates_t[quad*4+i][w*32 + 16 + fr] = acc1[i];
    }
    __syncthreads();

    float hv0, hv1;
    {
      int u = ul;
      float gi = gates_t[chunk][      u] + gxv[0];
      float gf = gates_t[chunk][ 64 + u] + gxv[1];
      float gg = gates_t[chunk][128 + u] + gxv[2];
      float go = gates_t[chunk][192 + u] + gxv[3];
      float si = 1.f/(1.f + __expf(-gi));
      float sf = 1.f/(1.f + __expf(-gf));
      float tg = 1.f - 2.f/(1.f + __expf(2.f*gg));
      c0 = sf*c0 + si*tg;
      float th = 1.f - 2.f/(1.f + __expf(2.f*c0));
      hv0 = (1.f/(1.f + __expf(-go))) * th;
    }
    {
      int u = ul + 32;
      float gi = gates_t[chunk][      u] + gxv[4];
      float gf = gates_t[chunk][ 64 + u] + gxv[5];
      float gg = gates_t[chunk][128 + u] + gxv[6];
      float go = gates_t[chunk][192 + u] + gxv[7];
      float si = 1.f/(1.f + __expf(-gi));
      float sf = 1.f/(1.f + __expf(-gf));
      float tg = 1.f - 2.f/(1.f + __expf(2.f*gg));
      c1 = sf*c1 + si*tg;
      float th = 1.f - 2.f/(1.f + __expf(2.f*c1));
      hv1 = (1.f/(1.f + __expf(-go))) * th;
    }
    // own h -> local LDS + packed-bf16 LLC publish + payload store
    u16 hb0 = f2bf(hv0), hb1 = f2bf(hv1);
    h_bf[par^1][chunk][blk*64 + ul     ] = hb0;
    h_bf[par^1][chunk][blk*64 + ul + 32] = hb1;
    unsigned pk = (unsigned)hb0 | ((unsigned)hb1 << 16);
    __hip_atomic_store(&pub_t[par*(TPB_TEAM*512) + blk*512 + chunk*32 + ul],
                       pk, __ATOMIC_RELAXED, __HIP_MEMORY_SCOPE_AGENT);
    if (s >= cstart && s < cend){
      hout[(size_t)s*HID + blk*64 + ul     ] = hv0;
      hout[(size_t)s*HID + blk*64 + ul + 32] = hv1;
    }
    __syncthreads();                     // vmcnt(0): pub stores LLC-ack'd
    if (t == 0)
      __hip_atomic_store(flag_self, sl+1, __ATOMIC_RELAXED, __HIP_MEMORY_SCOPE_AGENT);
    if (t < 4){
      int rb = t + (t >= blk);
      int* rf = flags + (team*TPB_TEAM + rb)*32;
      while (__hip_atomic_load(rf, __ATOMIC_RELAXED, __HIP_MEMORY_SCOPE_AGENT) <= sl)
        __builtin_amdgcn_s_sleep(1);
    }
    __syncthreads();
    // pull 4 remote packed slices (8KB) into h_bf[par^1]
    {
      int ch = t >> 5, uu = t & 31;
      #pragma unroll
      for (int j = 0; j < 4; ++j){
        int rb = j + (j >= blk);
        unsigned pk2 = __hip_atomic_load(&pub_t[par*(TPB_TEAM*512) + rb*512 + t],
                                         __ATOMIC_RELAXED, __HIP_MEMORY_SCOPE_AGENT);
        h_bf[par^1][ch][rb*64 + uu     ] = (u16)(pk2 & 0xFFFFu);
        h_bf[par^1][ch][rb*64 + uu + 32] = (u16)(pk2 >> 16);
      }
    }
    __syncthreads();
  }
}

// ---------------- GCN: CSR build (counting sort by dst) + gather ----------------
__global__ void k_hist(const int* __restrict__ ei, int* deg){
  int e = blockIdx.x*256 + threadIdx.x;
  if (e < NE) atomicAdd(&deg[ei[NE + e]], 1);
}

__global__ void k_offsets(const int* __restrict__ deg, int* off, int* cursor){
  __shared__ int sdata[1024];
  int t = threadIdx.x;
  int loc[8]; int s = 0;
  #pragma unroll
  for (int j = 0; j < 8; j++){ loc[j] = deg[t*8 + j]; s += loc[j]; }
  sdata[t] = s; __syncthreads();
  for (int d = 1; d < 1024; d <<= 1){
    int add = (t >= d) ? sdata[t-d] : 0;
    __syncthreads();
    sdata[t] += add;
    __syncthreads();
  }
  int run = sdata[t] - s;
  #pragma unroll
  for (int j = 0; j < 8; j++){ off[t*8+j] = run; cursor[t*8+j] = run; run += loc[j]; }
  if (t == 1023) off[NN] = run;
}

__global__ void k_scatter(const int* __restrict__ ei, const float* __restrict__ ew,
                          int* cursor, int* esrc, float* ews){
  int e = blockIdx.x*256 + threadIdx.x;
  if (e < NE){
    int d = ei[NE + e];
    int p = atomicAdd(&cursor[d], 1);
    esrc[p] = ei[e];
    ews[p] = ew[e];
  }
}

__global__ void k_gather(const float* __restrict__ XW, int F,
    const int* __restrict__ off, const int* __restrict__ esrc, const float* __restrict__ ews,
    const float* __restrict__ bias, u16* outb, float* outf, int ldout, int lrFlag)
{
  int node = blockIdx.x*4 + (threadIdx.x >> 6);
  int lane = threadIdx.x & 63;
  float acc[5] = {0,0,0,0,0};
  int e0 = off[node], e1 = off[node+1];
  for (int e = e0; e < e1; ++e){
    int sN = esrc[e]; float we = ews[e];
    const float* xr = XW + (size_t)sN*F;
    #pragma unroll
    for (int j = 0; j < 5; j++){
      int f = j*64 + lane;
      if (f < F) acc[j] += we * xr[f];
    }
  }
  #pragma unroll
  for (int j = 0; j < 5; j++){
    int f = j*64 + lane;
    if (f < F){
      float v = acc[j] + bias[f];
      if (lrFlag) v = lrelu(v);
      if (outb) outb[(size_t)node*ldout + f] = f2bf(v);
      else      outf[(size_t)node*F + f] = v;
    }
  }
  if (outb){
    for (int f = F + lane; f < ldout; f += 64) outb[(size_t)node*ldout + f] = 0;
  }
}

// ---------------- BN stats + fused BN/pool/FC ----------------
__global__ void k_bnstats(const float* __restrict__ conv4, float* mu, float* iv){
  int f = blockIdx.x, t = threadIdx.x;
  float s = 0, ss = 0;
  for (int i = t; i < NN; i += 256){ float v = conv4[(size_t)i*50 + f]; s += v; ss += v*v; }
  __shared__ float S[256], SS[256];
  S[t] = s; SS[t] = ss; __syncthreads();
  for (int d = 128; d > 0; d >>= 1){ if (t < d){ S[t] += S[t+d]; SS[t] += SS[t+d]; } __syncthreads(); }
  if (t == 0){
    float m = S[0] / (float)NN;
    float var = SS[0] / (float)NN - m*m;
    mu[f] = m; iv[f] = rsqrtf(var + 1e-5f);
  }
}

__global__ void k_final(const float* __restrict__ conv4, const float* __restrict__ mu,
    const float* __restrict__ iv, const float* __restrict__ gamma, const float* __restrict__ beta,
    const float* __restrict__ f1W, const float* __restrict__ f1b,
    const float* __restrict__ f2W, const float* __restrict__ f2b,
    const float* __restrict__ f3W, const float* __restrict__ f3b, float* __restrict__ out)
{
  int g = blockIdx.x, t = threadIdx.x;
  __shared__ float pl[50]; __shared__ float o1[30]; __shared__ float o2[20];
  if (t < 50){
    float mf = mu[t], ivf = iv[t], ga = gamma[t], be = beta[t];
    float s = 0;
    for (int i = 0; i < 8; i++){
      float v = conv4[(size_t)(g*8+i)*50 + t];
      v = ga*(v - mf)*ivf + be;
      s += lrelu(v);
    }
    pl[t] = s;
  }
  __syncthreads();
  if (t < 30){ float a = f1b[t]; for (int f = 0; f < 50; f++) a += pl[f]*f1W[f*30+t]; o1[t] = lrelu(a); }
  __syncthreads();
  if (t < 20){ float a = f2b[t]; for (int j = 0; j < 30; j++) a += o1[j]*f2W[j*20+t]; o2[t] = lrelu(a); }
  __syncthreads();
  if (t < 2){  float a = f3b[t]; for (int j = 0; j < 20; j++) a += o2[j]*f3W[j*2+t]; out[g*2+t] = lrelu(a); }
}

// ---------------- host ----------------
extern "C" void kernel_launch(void* const* d_in, const int* in_sizes, int n_in,
                              void* d_out, int out_size, void* d_ws, size_t ws_size,
                              hipStream_t stream) {
  const float* x    = (const float*)d_in[0];
  const int*   ei   = (const int*)  d_in[1];
  const float* ew   = (const float*)d_in[2];
  const float* Wih0 = (const float*)d_in[4];
  const float* Whh0 = (const float*)d_in[5];
  const float* bi0  = (const float*)d_in[6];
  const float* bh0  = (const float*)d_in[7];
  const float* Wih1 = (const float*)d_in[8];
  const float* Whh1 = (const float*)d_in[9];
  const float* bi1  = (const float*)d_in[10];
  const float* bh1  = (const float*)d_in[11];
  const float* Wg1  = (const float*)d_in[12];
  const float* bg1  = (const float*)d_in[13];
  const float* Wg2  = (const float*)d_in[14];
  const float* bg2  = (const float*)d_in[15];
  const float* Wg3  = (const float*)d_in[16];
  const float* bg3  = (const float*)d_in[17];
  const float* Wg4  = (const float*)d_in[18];
  const float* bg4  = (const float*)d_in[19];
  const float* gam  = (const float*)d_in[20];
  const float* bet  = (const float*)d_in[21];
  const float* f1W  = (const float*)d_in[22];
  const float* f1b  = (const float*)d_in[23];
  const float* f2W  = (const float*)d_in[24];
  const float* f2b  = (const float*)d_in[25];
  const float* f3W  = (const float*)d_in[26];
  const float* f3b  = (const float*)d_in[27];

  char* ws = (char*)d_ws;
  size_t o = 0;
  auto alloc = [&](size_t bytes)->char*{ char* p = ws + o; o += (bytes + 255) & ~(size_t)255; return p; };
  float* gx    = (float*)alloc((size_t)NN*FOUR_H*4);
  float* hseq  = (float*)alloc((size_t)NN*HID*4);
  u16*   actA  = (u16*)  alloc((size_t)NN*FIN*2);
  u16*   actB  = (u16*)  alloc((size_t)NN*HID*2);
  float* XW    = (float*)alloc((size_t)NN*HID*4);
  float* conv4 = (float*)alloc((size_t)NN*50*4);
  u16*   Wih0b = (u16*)  alloc((size_t)1280*1280*2);
  u16*   Wih1b = (u16*)  alloc((size_t)1280*320*2);
  u16*   Whh0b = (u16*)  alloc((size_t)1280*320*2);
  u16*   Whh1b = (u16*)  alloc((size_t)1280*320*2);
  u16*   W1T   = (u16*)  alloc((size_t)320*320*2);
  u16*   W2T   = (u16*)  alloc((size_t)192*320*2);
  u16*   W3T   = (u16*)  alloc((size_t)128*192*2);
  u16*   W4T   = (u16*)  alloc((size_t)64*96*2);
  float* bs0   = (float*)alloc(1280*4);
  float* bs1   = (float*)alloc(1280*4);
  float* mu    = (float*)alloc(256);
  float* iv    = (float*)alloc(256);
  int*   deg   = (int*)  alloc(NN*4);
  int*   off   = (int*)  alloc((NN+1)*4);
  int*   cursor= (int*)  alloc(NN*4);
  int*   esrc  = (int*)  alloc((size_t)NE*4);
  float* ews   = (float*)alloc((size_t)NE*4);
  unsigned* pub= (unsigned*)alloc((size_t)TEAMS*2*TPB_TEAM*512*4);
  int*   flags0= (int*)  alloc((size_t)TEAMS*TPB_TEAM*32*4);
  int*   flags1= (int*)  alloc((size_t)TEAMS*TPB_TEAM*32*4);
  (void)ws_size; (void)in_sizes; (void)n_in; (void)out_size;

  // prep
  k_zero<<<32, 256, 0, stream>>>(deg, flags0, flags1);
  k_bias<<<10, 256, 0, stream>>>(bi0, bh0, bi1, bh1, bs0, bs1);
  k_cvt<<<dim3(5, NN),   256, 0, stream>>>(x,    actA,  1280, 1280, 0);
  k_cvt<<<dim3(5, 1280), 256, 0, stream>>>(Wih0, Wih0b, 1280, 1280, 0);
  k_cvt<<<dim3(2, 1280), 256, 0, stream>>>(Wih1, Wih1b, 320,  320,  0);
  k_cvt<<<dim3(2, 1280), 256, 0, stream>>>(Whh0, Whh0b, 320,  320,  0);
  k_cvt<<<dim3(2, 1280), 256, 0, stream>>>(Whh1, Whh1b, 320,  320,  0);
  k_wT<<<dim3(320, 2), 256, 0, stream>>>(Wg1, W1T, 320, 320, 320);
  k_wT<<<dim3(192, 2), 256, 0, stream>>>(Wg2, W2T, 320, 180, 320);
  k_wT<<<dim3(128, 1), 256, 0, stream>>>(Wg3, W3T, 180, 90, 192);
  k_wT<<<dim3(64, 1),  256, 0, stream>>>(Wg4, W4T, 90, 50, 96);
  // CSR build
  k_hist<<<512, 256, 0, stream>>>(ei, deg);
  k_offsets<<<1, 1024, 0, stream>>>(deg, off, cursor);
  k_scatter<<<512, 256, 0, stream>>>(ei, ew, cursor, esrc, ews);

  // LSTM layer 0
  gemm_bt<<<dim3(128, 20), 256, 0, stream>>>(actA, 1280, Wih0b, 1280, gx, 1280, 1280, 40, bs0);
  {
    const float* a0 = gx; const u16* a1 = Whh0b; float* a2 = hseq; unsigned* a3 = pub; int* a4 = flags0;
    void* kargs[5] = {&a0, &a1, &a2, &a3, &a4};
    if (hipLaunchCooperativeKernel((const void*)lstm_scan, dim3(TEAMS*TPB_TEAM), dim3(512),
                                   kargs, 0, stream) != hipSuccess)
      lstm_scan<<<dim3(TEAMS*TPB_TEAM), 512, 0, stream>>>(a0, a1, a2, a3, a4);
  }
  // LSTM layer 1
  k_cvt<<<dim3(2, NN), 256, 0, stream>>>(hseq, actB, 320, 320, 0);
  gemm_bt<<<dim3(128, 20), 256, 0, stream>>>(actB, 320, Wih1b, 320, gx, 1280, 1280, 10, bs1);
  {
    const float* a0 = gx; const u16* a1 = Whh1b; float* a2 = hseq; unsigned* a3 = pub; int* a4 = flags1;
    void* kargs[5] = {&a0, &a1, &a2, &a3, &a4};
    if (hipLaunchCooperativeKernel((const void*)lstm_scan, dim3(TEAMS*TPB_TEAM), dim3(512),
                                   kargs, 0, stream) != hipSuccess)
      lstm_scan<<<dim3(TEAMS*TPB_TEAM), 512, 0, stream>>>(a0, a1, a2, a3, a4);
  }
  k_cvt<<<dim3(2, NN), 256, 0, stream>>>(hseq, actA, 320, 320, 1);

  // GCN stack
  gemm_bt<<<dim3(128, 5), 256, 0, stream>>>(actA, 320, W1T, 320, XW, 320, 320, 10, nullptr);
  k_gather<<<2048, 256, 0, stream>>>(XW, 320, off, esrc, ews, bg1, actB, nullptr, 320, 1);
  gemm_bt<<<dim3(128, 3), 256, 0, stream>>>(actB, 320, W2T, 320, XW, 180, 180, 10, nullptr);
  k_gather<<<2048, 256, 0, stream>>>(XW, 180, off, esrc, ews, bg2, actA, nullptr, 192, 1);
  gemm_bt<<<dim3(128, 2), 256, 0, stream>>>(actA, 192, W3T, 192, XW, 90, 90, 6, nullptr);
  k_gather<<<2048, 256, 0, stream>>>(XW, 90, off, esrc, ews, bg3, actB, nullptr, 96, 1);
  gemm_bt<<<dim3(128, 1), 256, 0, stream>>>(actB, 96, W4T, 96, XW, 50, 50, 3, nullptr);
  k_gather<<<2048, 256, 0, stream>>>(XW, 50, off, esrc, ews, bg4, nullptr, conv4, 50, 0);

  // BN + pool + FC head
  k_bnstats<<<50, 256, 0, stream>>>(conv4, mu, iv);
  k_final<<<NG, 64, 0, stream>>>(conv4, mu, iv, gam, bet, f1W, f1b, f2W, f2b, f3W, f3b,
                                 (float*)d_out);
}